// Round 8
// baseline (290.105 us; speedup 1.0000x reference)
//
#include <hip/hip_runtime.h>

#define NV 16384
#define JT 256            // j per step (64 lanes x 4 floats)
#define NT (NV / JT)      // 64 steps
#define ROWS 8            // L rows per wave

typedef const __attribute__((address_space(1))) void* as1_ptr;
typedef __attribute__((address_space(3))) void* as3_ptr;

__device__ __forceinline__ void gload_lds16(const float* g, float* l) {
  __builtin_amdgcn_global_load_lds((as1_ptr)g, (as3_ptr)l, 16, 0, 0);
}

#define FENCE asm volatile("" ::: "memory")
#define WAITV(n) asm volatile("s_waitcnt vmcnt(" #n ")" ::: "memory")

// 1 wave per block, wave-private LDS, NO barriers anywhere.
__global__ __launch_bounds__(64, 2) void lap_loss_kernel(
    const float* __restrict__ x, const float* __restrict__ L,
    float* __restrict__ out) {
  __shared__ float lbuf[2][ROWS][JT];  // 16 KB, private to this wave

  const int lane = threadIdx.x & 63;
  const size_t i0 = (size_t)blockIdx.x * ROWS;

  const float* gL[ROWS];
#pragma unroll
  for (int r = 0; r < ROWS; ++r) gL[r] = L + (i0 + r) * NV + lane * 4;

  const float* gx[4];
#pragma unroll
  for (int b = 0; b < 4; ++b) gx[b] = x + (size_t)b * NV * 3 + lane * 12;

  float acc[ROWS][4][3];
#pragma unroll
  for (int r = 0; r < ROWS; ++r)
#pragma unroll
    for (int b = 0; b < 4; ++b)
#pragma unroll
      for (int d = 0; d < 3; ++d) acc[r][b][d] = 0.f;

  float4 xn[12];     // x(t+1) in flight
  float  xf[48];     // x(t) unpacked, consumed by FMAs

  // ---- prologue: x(0) (oldest), then L(0) gl_lds (newest) ----
#pragma unroll
  for (int b = 0; b < 4; ++b) {
    const float4* p = (const float4*)gx[b];
    xn[b * 3 + 0] = p[0]; xn[b * 3 + 1] = p[1]; xn[b * 3 + 2] = p[2];
  }
  FENCE;
#pragma unroll
  for (int r = 0; r < ROWS; ++r) gload_lds16(gL[r], &lbuf[0][r][0]);
  FENCE;
  // unpack x(0) (compiler inserts the wait on xn here)
#pragma unroll
  for (int i = 0; i < 12; ++i) {
    xf[i * 4 + 0] = xn[i].x; xf[i * 4 + 1] = xn[i].y;
    xf[i * 4 + 2] = xn[i].z; xf[i * 4 + 3] = xn[i].w;
  }

  auto body = [&](int t, int cur) {
#pragma unroll
    for (int r = 0; r < ROWS; ++r) {
      float4 lv = *(const float4*)&lbuf[cur][r][lane * 4];
      const float lf[4] = {lv.x, lv.y, lv.z, lv.w};
#pragma unroll
      for (int q = 0; q < 4; ++q)
#pragma unroll
        for (int b = 0; b < 4; ++b)
#pragma unroll
          for (int d = 0; d < 3; ++d)
            acc[r][b][d] =
                fmaf(lf[q], xf[b * 12 + q * 3 + d], acc[r][b][d]);
    }
  };

#pragma unroll 1
  for (int t = 0; t < NT - 1; ++t) {
    const int cur = t & 1;

    // issue x(t+1) FIRST (older in queue than L: any wait on x keeps L alive)
#pragma unroll
    for (int b = 0; b < 4; ++b) {
      const float4* p = (const float4*)(gx[b] + (size_t)(t + 1) * JT * 3);
      xn[b * 3 + 0] = p[0]; xn[b * 3 + 1] = p[1]; xn[b * 3 + 2] = p[2];
    }
    FENCE;
    // issue L(t+1) gl_lds into the other private buffer (8 newest)
#pragma unroll
    for (int r = 0; r < ROWS; ++r)
      gload_lds16(gL[r] + (size_t)(t + 1) * JT, &lbuf[cur ^ 1][r][0]);
    FENCE;
    // retire x(t)+L(t) (a full step old -> no stall);
    // keep x(t+1)x12 + L(t+1)x8 = 20 in flight through the compute phase
    WAITV(20);

    body(t, cur);

    __builtin_amdgcn_sched_barrier(0);  // pin unpack below the FMAs
    WAITV(8);                            // retire x(t+1); keep 8 L gl_lds
#pragma unroll
    for (int i = 0; i < 12; ++i) {
      xf[i * 4 + 0] = xn[i].x; xf[i * 4 + 1] = xn[i].y;
      xf[i * 4 + 2] = xn[i].z; xf[i * 4 + 3] = xn[i].w;
    }
  }

  // ---- last step: drain, compute ----
  WAITV(0);
  body(NT - 1, (NT - 1) & 1);

  // ---- butterfly-reduce each (r,b,d) over 64 lanes, square, commit ----
  float s[4] = {0.f, 0.f, 0.f, 0.f};
#pragma unroll
  for (int r = 0; r < ROWS; ++r)
#pragma unroll
    for (int b = 0; b < 4; ++b)
#pragma unroll
      for (int d = 0; d < 3; ++d) {
        float v = acc[r][b][d];
#pragma unroll
        for (int off = 32; off > 0; off >>= 1)
          v += __shfl_xor(v, off, 64);
        s[b] += v * v;
      }

  if (lane == 0) {
#pragma unroll
    for (int b = 0; b < 4; ++b) atomicAdd(&out[b], s[b]);
  }
}

extern "C" void kernel_launch(void* const* d_in, const int* in_sizes, int n_in,
                              void* d_out, int out_size, void* d_ws, size_t ws_size,
                              hipStream_t stream) {
  const float* x = (const float*)d_in[0];
  const float* L = (const float*)d_in[1];
  float* out = (float*)d_out;

  // Harness poisons d_out with 0xAA and never re-poisons between replays.
  hipMemsetAsync(out, 0, out_size * sizeof(float), stream);

  const int nblocks = NV / ROWS;  // 2048 one-wave blocks = 8/CU, one exact round
  lap_loss_kernel<<<nblocks, 64, 0, stream>>>(x, L, out);
}

// Round 10
// 261.448 us; speedup vs baseline: 1.1096x; 1.1096x over previous
//
#include <hip/hip_runtime.h>

#define NV 16384
#define BROWS 16          // L rows per block; 4 staged per wave
#define JT 256            // j-tile width (floats); tile = 16 KB
#define NT (NV / JT)      // 64 tiles
#define THREADS 256

typedef const __attribute__((address_space(1))) void* as1_ptr;
typedef __attribute__((address_space(3))) void* as3_ptr;

__device__ __forceinline__ void gload_lds16(const float* g, float* l) {
  __builtin_amdgcn_global_load_lds((as1_ptr)g, (as3_ptr)l, 16, 0, 0);
}

#define FENCE asm volatile("" ::: "memory")
#define WAITV(n) asm volatile("s_waitcnt vmcnt(" #n ")" ::: "memory")
#define BARRIER __builtin_amdgcn_s_barrier()

__global__ __launch_bounds__(THREADS, 2) void lap_loss_kernel(
    const float* __restrict__ x, const float* __restrict__ L,
    float* __restrict__ out) {
  __shared__ float lbuf[4][BROWS][JT];  // 4-deep rotation, 64 KB

  const int lane = threadIdx.x & 63;
  const int w    = threadIdx.x >> 6;     // wave id == batch index b
  const size_t i0 = (size_t)blockIdx.x * BROWS;

  // wave w stages rows i0+4w .. i0+4w+3; lane covers 16B of each row
  const float* gL0 = L + (i0 + 4 * w + 0) * NV + lane * 4;
  const float* gL1 = L + (i0 + 4 * w + 1) * NV + lane * 4;
  const float* gL2 = L + (i0 + 4 * w + 2) * NV + lane * 4;
  const float* gL3 = L + (i0 + 4 * w + 3) * NV + lane * 4;

  // wave w's x stream: x[w][j][d], lane owns j-quad 4*lane (48B)
  const float* gx = x + (size_t)w * NV * 3 + lane * 12;

  float acc[BROWS][3];
#pragma unroll
  for (int r = 0; r < BROWS; ++r)
#pragma unroll
    for (int d = 0; d < 3; ++d) acc[r][d] = 0.f;

  // x prefetch slots — ONLY ever indexed with compile-time constants
  // (fully unrolled), so they live in registers.
  float4 xpf[4][3];

// Issue tile T into slot S: x loads FIRST (older in FIFO), then 4 gl_lds.
// Waiting for tile T's gl_lds later auto-retires its x loads -> the
// compiler never needs an implicit vmcnt for the x registers.
#define ISSUE(T, S) do {                                               \
    const float4* _p = (const float4*)(gx + (size_t)(T) * JT * 3);     \
    xpf[S][0] = _p[0]; xpf[S][1] = _p[1]; xpf[S][2] = _p[2];           \
    FENCE;                                                             \
    gload_lds16(gL0 + (size_t)(T) * JT, &lbuf[S][4 * w + 0][0]);       \
    gload_lds16(gL1 + (size_t)(T) * JT, &lbuf[S][4 * w + 1][0]);       \
    gload_lds16(gL2 + (size_t)(T) * JT, &lbuf[S][4 * w + 2][0]);       \
    gload_lds16(gL3 + (size_t)(T) * JT, &lbuf[S][4 * w + 3][0]);       \
    FENCE;                                                             \
  } while (0)

#define COMPUTE(S) do {                                                \
    const float xf[12] = {xpf[S][0].x, xpf[S][0].y, xpf[S][0].z,       \
                          xpf[S][0].w, xpf[S][1].x, xpf[S][1].y,       \
                          xpf[S][1].z, xpf[S][1].w, xpf[S][2].x,       \
                          xpf[S][2].y, xpf[S][2].z, xpf[S][2].w};      \
    _Pragma("unroll")                                                  \
    for (int r = 0; r < BROWS; ++r) {                                  \
      float4 lv = *(const float4*)&lbuf[S][r][lane * 4];               \
      const float lf[4] = {lv.x, lv.y, lv.z, lv.w};                    \
      _Pragma("unroll")                                                \
      for (int q = 0; q < 4; ++q)                                      \
        _Pragma("unroll")                                              \
        for (int d = 0; d < 3; ++d)                                    \
          acc[r][d] = fmaf(lf[q], xf[q * 3 + d], acc[r][d]);           \
    }                                                                  \
  } while (0)

// Steady-state step at tile T (slot SC = T%4): issue T+3 into slot SI,
// wait vmcnt(21) = keep tiles T+1,T+2,T+3 (7 instrs each) in flight,
// barrier, compute tile T, barrier.
#define STEP_FULL(T, SI, SC) do {                                      \
    ISSUE((T) + 3, SI);                                                \
    WAITV(21);                                                         \
    BARRIER; FENCE;                                                    \
    COMPUTE(SC);                                                       \
    FENCE; BARRIER; FENCE;                                             \
  } while (0)

  // ---- prologue: tiles 0,1,2 in flight (21 instrs outstanding) ----
  ISSUE(0, 0);
  ISSUE(1, 1);
  ISSUE(2, 2);

  // ---- main loop: t = 0..59 ----
#pragma unroll 1
  for (int k = 0; k < 15; ++k) {
    const int t = 4 * k;
    STEP_FULL(t + 0, 3, 0);
    STEP_FULL(t + 1, 0, 1);
    STEP_FULL(t + 2, 1, 2);
    STEP_FULL(t + 3, 2, 3);
  }

  // ---- epilogue: t = 60..63, draining 21 -> 0 ----
  ISSUE(63, 3);
  WAITV(21); BARRIER; FENCE;
  COMPUTE(0);
  FENCE; BARRIER; FENCE;

  WAITV(14); BARRIER; FENCE;
  COMPUTE(1);
  FENCE; BARRIER; FENCE;

  WAITV(7); BARRIER; FENCE;
  COMPUTE(2);
  FENCE; BARRIER; FENCE;

  WAITV(0); BARRIER; FENCE;
  COMPUTE(3);

  // ---- butterfly-reduce each (row,d) partial over 64 lanes, square ----
  float s = 0.f;
#pragma unroll
  for (int r = 0; r < BROWS; ++r)
#pragma unroll
    for (int d = 0; d < 3; ++d) {
      float v = acc[r][d];
#pragma unroll
      for (int off = 32; off > 0; off >>= 1)
        v += __shfl_xor(v, off, 64);
      s += v * v;
    }

  if (lane == 0) atomicAdd(&out[w], s);  // wave w owns batch w
}

extern "C" void kernel_launch(void* const* d_in, const int* in_sizes, int n_in,
                              void* d_out, int out_size, void* d_ws, size_t ws_size,
                              hipStream_t stream) {
  const float* x = (const float*)d_in[0];
  const float* L = (const float*)d_in[1];
  float* out = (float*)d_out;

  // Harness poisons d_out with 0xAA and never re-poisons between replays.
  hipMemsetAsync(out, 0, out_size * sizeof(float), stream);

  const int nblocks = NV / BROWS;  // 1024 blocks = 2 resident/CU, 2 rounds
  lap_loss_kernel<<<nblocks, THREADS, 0, stream>>>(x, L, out);
}